// Round 1
// baseline (307.656 us; speedup 1.0000x reference)
//
#include <hip/hip_runtime.h>
#include <hip/hip_fp16.h>

// Problem constants (from reference)
#define N0C 4096
#define E0C 16384
#define N1C 1024
#define E1C 8192
#define HC 64          // hidden / channels
#define FINC 8
#define LATC 32
#define FC 67          // H + DIM

typedef float f32x4 __attribute__((ext_vector_type(4)));
typedef _Float16 f16x8 __attribute__((ext_vector_type(8)));

// ---------------- encoder: h0 = sin(0.01*(x@lin0_w + lin0_b)) ----------------
__global__ void k_encoder(const float* __restrict__ x, const float* __restrict__ w,
                          const float* __restrict__ b, float* __restrict__ h0) {
  int id = blockIdx.x * blockDim.x + threadIdx.x;
  if (id >= N0C * HC) return;
  int n = id >> 6, j = id & 63;
  float a = b[j];
#pragma unroll
  for (int f = 0; f < FINC; ++f) a = fmaf(x[n * FINC + f], w[f * HC + j], a);
  h0[id] = sinf(0.01f * a);
}

// ---------------- channel basis: cB/sB[c,h] = cos/sin(0.1*c*w0[3,h]) ---------
__global__ void k_chanprep(const float* __restrict__ kw0, float* __restrict__ cB,
                           float* __restrict__ sB) {
  int id = blockIdx.x * blockDim.x + threadIdx.x;  // c*64+h
  if (id >= HC * HC) return;
  int c = id >> 6, hh = id & 63;
  float arg = 0.1f * (float)c * kw0[3 * HC + hh];
  float s, cv;
  sincosf(arg, &s, &cv);
  sB[id] = s;
  cB[id] = cv;
}

// ---------------- per-edge prep: sA/cA = sin/cos(0.1*base), t, d -------------
__global__ void k_edgeprep(const int* __restrict__ ei, int E, int eBase,
                           const float* __restrict__ posp,
                           const float* __restrict__ hbuf,
                           const float* __restrict__ kw0, const float* __restrict__ kb0,
                           const float* __restrict__ kw2, const float* __restrict__ kb2,
                           float* __restrict__ sA, float* __restrict__ cA,
                           float* __restrict__ tbuf, float* __restrict__ dp) {
  const int el = blockIdx.x;
  const int e = eBase + el;
  const int lane = threadIdx.x;  // 64 threads = 1 wave
  int s, d2;
  if (e < E) { s = ei[e]; d2 = ei[E + e]; } else { s = e - E; d2 = s; }
  const float px = posp[s * 3 + 0], py = posp[s * 3 + 1], pz = posp[s * 3 + 2];
  const float rx = posp[d2 * 3 + 0] - px;
  const float ry = posp[d2 * 3 + 1] - py;
  const float rz = posp[d2 * 3 + 2] - pz;
  float f0 = 0.f, f1 = 0.f, f2 = 0.f;
  if (!(rx == 0.f && ry == 0.f && rz == 0.f)) {
    const float PI_F = 3.14159265358979323846f;
    float rho = sqrtf(rx * rx + ry * ry + rz * rz);
    float th = atan2f(ry, rx);
    float ratio = rz / rho;
    ratio = fminf(1.f, fmaxf(-1.f, ratio));
    float ph = asinf(ratio);
    f0 = rho;
    f1 = th / PI_F;
    f2 = ph / PI_F;
  }
  float base = kb0[lane];
  base = fmaf(f0, kw0[0 * HC + lane], base);
  base = fmaf(f1, kw0[1 * HC + lane], base);
  base = fmaf(f2, kw0[2 * HC + lane], base);
  float sv, cv;
  sincosf(0.1f * base, &sv, &cv);
  sA[el * HC + lane] = sv;
  cA[el * HC + lane] = cv;
  // t[e,k] = sum_f w2[k,f] * xj[f]   (xj = [hbuf[src] || pos[src]])
  const float* xrow = hbuf + (size_t)s * HC;
  const float* wrow = kw2 + lane * FC;
  float acc = 0.f;
#pragma unroll 8
  for (int f = 0; f < HC; ++f) acc = fmaf(wrow[f], xrow[f], acc);
  acc = fmaf(wrow[64], px, acc);
  acc = fmaf(wrow[65], py, acc);
  acc = fmaf(wrow[66], pz, acc);
  tbuf[el * HC + lane] = acc;
  // d[e] = xj . b2
  float pd = xrow[lane] * kb2[lane];
  if (lane == 0) pd = fmaf(px, kb2[64], pd);
  if (lane == 1) pd = fmaf(py, kb2[65], pd);
  if (lane == 2) pd = fmaf(pz, kb2[66], pd);
#pragma unroll
  for (int m = 1; m < 64; m <<= 1) pd += __shfl_xor(pd, m, 64);
  if (lane == 0) dp[e] = pd;
}

// ---------------- conv core: per-edge 64x64x64 MFMA GEMM + fused epilogue ----
// A[c,h] = sA[e,h]*cB[c,h] + cA[e,h]*sB[c,h]   (built fp16 in LDS, lane=c)
// B[h,k] = w1[h,k]                              (fp16, staged transposed in LDS)
// z = A@B ; msg[e,c] = sum_k sin(0.1*z+0.1*b1[k]) * t[e,k] + d[e]
// atomicAdd into accout[dst,c]
__global__ __launch_bounds__(256) void k_conv(
    const int* __restrict__ ei, int E, int eBase, int eLen,
    const float* __restrict__ sA, const float* __restrict__ cA,
    const float* __restrict__ tbuf, const float* __restrict__ dp,
    const float* __restrict__ cB, const float* __restrict__ sB,
    const float* __restrict__ w1, const float* __restrict__ b1,
    float* __restrict__ accout) {
  // A rows padded 64->72 halves to spread LDS banks; Bt[n][k] = w1[k*64+n]
  __shared__ __attribute__((aligned(16))) _Float16 Atile[4][64][72];
  __shared__ __attribute__((aligned(16))) _Float16 Bt[64][72];
  const int tid = threadIdx.x;
  const int wave = __builtin_amdgcn_readfirstlane(tid >> 6);
  const int lane = tid & 63;
  const int m_row = lane & 15, q = lane >> 4;

  // stage w1 transposed into LDS (coalesced global reads)
  for (int idx = tid; idx < HC * HC; idx += 256) {
    int n = idx & 63, k = idx >> 6;
    Bt[n][k] = (_Float16)w1[k * HC + n];
  }
  float b1s[4];
#pragma unroll
  for (int nt = 0; nt < 4; ++nt) b1s[nt] = 0.1f * b1[nt * 16 + m_row];
  __syncthreads();  // Bt ready (uniform: before any divergent edge loop)

  const int nWaves = gridDim.x * 4;
  for (int el = blockIdx.x * 4 + wave; el < eLen; el += nWaves) {
    const int e = eBase + el;
    const float* sAe = sA + el * HC;  // wave-uniform -> scalar loads
    const float* cAe = cA + el * HC;
    const float* cBr = cB + lane * HC;  // lane = channel row c
    const float* sBr = sB + lane * HC;
    _Float16* myrow = &Atile[wave][lane][0];
#pragma unroll
    for (int h8 = 0; h8 < 8; ++h8) {
      f32x4 cb0 = *(const f32x4*)(cBr + h8 * 8);
      f32x4 cb1 = *(const f32x4*)(cBr + h8 * 8 + 4);
      f32x4 sb0 = *(const f32x4*)(sBr + h8 * 8);
      f32x4 sb1 = *(const f32x4*)(sBr + h8 * 8 + 4);
      f16x8 vv;
#pragma unroll
      for (int j = 0; j < 4; ++j) {
        float v0 = fmaf(sAe[h8 * 8 + j], cb0[j], cAe[h8 * 8 + j] * sb0[j]);
        float v1 = fmaf(sAe[h8 * 8 + 4 + j], cb1[j], cAe[h8 * 8 + 4 + j] * sb1[j]);
        vv[j] = (_Float16)v0;
        vv[4 + j] = (_Float16)v1;
      }
      *(f16x8*)(myrow + h8 * 8) = vv;
    }
    __builtin_amdgcn_wave_barrier();  // per-wave private tile; keep order

    f32x4 acc[4][4];
    const f32x4 zero = {0.f, 0.f, 0.f, 0.f};
#pragma unroll
    for (int ms = 0; ms < 4; ++ms)
#pragma unroll
      for (int nt = 0; nt < 4; ++nt) acc[ms][nt] = zero;

    const _Float16* Aw = &Atile[wave][0][0];
#pragma unroll
    for (int ks = 0; ks < 2; ++ks) {
      f16x8 bf[4];
#pragma unroll
      for (int nt = 0; nt < 4; ++nt)
        bf[nt] = *(const f16x8*)(&Bt[nt * 16 + m_row][ks * 32 + q * 8]);
#pragma unroll
      for (int ms = 0; ms < 4; ++ms) {
        f16x8 af = *(const f16x8*)(Aw + (ms * 16 + m_row) * 72 + ks * 32 + q * 8);
#pragma unroll
        for (int nt = 0; nt < 4; ++nt)
          acc[ms][nt] = __builtin_amdgcn_mfma_f32_16x16x32_f16(af, bf[nt], acc[ms][nt], 0, 0, 0);
      }
    }

    // epilogue: D[row=c=(ms*16+q*4+r)][col=k=(nt*16+m_row)]
    float tr[4];
#pragma unroll
    for (int nt = 0; nt < 4; ++nt) tr[nt] = tbuf[el * HC + nt * 16 + m_row];
    float dval = dp[e];
    int dstn = (e < E) ? ei[E + e] : (e - E);
    float* orow = accout + (size_t)dstn * HC;
#pragma unroll
    for (int ms = 0; ms < 4; ++ms) {
      float p0 = 0.f, p1 = 0.f, p2 = 0.f, p3 = 0.f;
#pragma unroll
      for (int nt = 0; nt < 4; ++nt) {
        f32x4 z = acc[ms][nt];
        p0 = fmaf(__sinf(fmaf(0.1f, z[0], b1s[nt])), tr[nt], p0);
        p1 = fmaf(__sinf(fmaf(0.1f, z[1], b1s[nt])), tr[nt], p1);
        p2 = fmaf(__sinf(fmaf(0.1f, z[2], b1s[nt])), tr[nt], p2);
        p3 = fmaf(__sinf(fmaf(0.1f, z[3], b1s[nt])), tr[nt], p3);
      }
#pragma unroll
      for (int m = 1; m < 16; m <<= 1) {
        p0 += __shfl_xor(p0, m, 64);
        p1 += __shfl_xor(p1, m, 64);
        p2 += __shfl_xor(p2, m, 64);
        p3 += __shfl_xor(p3, m, 64);
      }
      if (m_row == 0) {
        int c0 = ms * 16 + q * 4;
        atomicAdd(orow + c0 + 0, p0 + dval);
        atomicAdd(orow + c0 + 1, p1 + dval);
        atomicAdd(orow + c0 + 2, p2 + dval);
        atomicAdd(orow + c0 + 3, p3 + dval);
      }
    }
  }
}

// ---------------- hc = sin(0.01*(acc + bias[c])) -----------------------------
__global__ void k_postsin(const float* __restrict__ acc, const float* __restrict__ bias,
                          float* __restrict__ outp, int total) {
  int id = blockIdx.x * blockDim.x + threadIdx.x;
  if (id >= total) return;
  outp[id] = sinf(0.01f * (acc[id] + bias[id & 63]));
}

// ---------------- max-pool over neighbors (incl self loops) ------------------
__global__ void k_poolmax(const int* __restrict__ ei, const float* __restrict__ hc,
                          unsigned* __restrict__ pb) {
  int id = blockIdx.x * blockDim.x + threadIdx.x;  // (E0+N0)*64
  int e = id >> 6, c = id & 63;
  int s, d2;
  if (e < E0C) { s = ei[e]; d2 = ei[E0C + e]; } else { s = e - E0C; d2 = s; }
  float v = hc[(size_t)s * HC + c];
  unsigned u = __float_as_uint(v);
  unsigned key = (u & 0x80000000u) ? ~u : (u | 0x80000000u);  // monotone map
  atomicMax(pb + (size_t)d2 * HC + c, key);
}

__global__ void k_gather(const unsigned* __restrict__ pb, const int* __restrict__ keep,
                         float* __restrict__ h1in) {
  int id = blockIdx.x * blockDim.x + threadIdx.x;  // N1*64
  if (id >= N1C * HC) return;
  int i = id >> 6, c = id & 63;
  unsigned key = pb[(size_t)keep[i] * HC + c];
  unsigned u = (key & 0x80000000u) ? (key ^ 0x80000000u) : ~key;
  h1in[id] = __uint_as_float(u);
}

// ---------------- final: out = sin(0.01*(hc1@lin1_w + lin1_b)) ---------------
__global__ void k_final(const float* __restrict__ hc1, const float* __restrict__ w,
                        const float* __restrict__ b, float* __restrict__ outp) {
  int id = blockIdx.x * blockDim.x + threadIdx.x;  // N1*LAT
  if (id >= N1C * LATC) return;
  int i = id >> 5, l = id & 31;
  float a = b[l];
#pragma unroll 8
  for (int c = 0; c < HC; ++c) a = fmaf(hc1[i * HC + c], w[c * LATC + l], a);
  outp[id] = sinf(0.01f * a);
}

extern "C" void kernel_launch(void* const* d_in, const int* in_sizes, int n_in,
                              void* d_out, int out_size, void* d_ws, size_t ws_size,
                              hipStream_t stream) {
  (void)in_sizes; (void)n_in; (void)out_size;
  const float* x    = (const float*)d_in[0];
  const float* pos  = (const float*)d_in[1];
  const int*   ei   = (const int*)d_in[2];
  const int*   pei  = (const int*)d_in[3];
  const float* ppos = (const float*)d_in[4];
  const int*   keep = (const int*)d_in[5];
  const float* l0w  = (const float*)d_in[6];
  const float* l0b  = (const float*)d_in[7];
  const float* l1w  = (const float*)d_in[8];
  const float* l1b  = (const float*)d_in[9];
  const float* c0w0 = (const float*)d_in[10];
  const float* c0b0 = (const float*)d_in[11];
  const float* c0w1 = (const float*)d_in[12];
  const float* c0b1 = (const float*)d_in[13];
  const float* c0w2 = (const float*)d_in[14];
  const float* c0b2 = (const float*)d_in[15];
  const float* c0bias = (const float*)d_in[16];
  const float* c1w0 = (const float*)d_in[17];
  const float* c1b0 = (const float*)d_in[18];
  const float* c1w1 = (const float*)d_in[19];
  const float* c1b1 = (const float*)d_in[20];
  const float* c1w2 = (const float*)d_in[21];
  const float* c1b2 = (const float*)d_in[22];
  const float* c1bias = (const float*)d_in[23];
  float* outp = (float*)d_out;

  char* p = (char*)d_ws;
  auto carve = [&](size_t bytes) -> char* {
    char* r = p;
    p += (bytes + 255) & ~(size_t)255;
    return r;
  };
  float* h0   = (float*)carve((size_t)N0C * HC * 4);
  float* acc0 = (float*)carve((size_t)N0C * HC * 4);
  float* hc0  = (float*)carve((size_t)N0C * HC * 4);
  unsigned* pb = (unsigned*)carve((size_t)N0C * HC * 4);
  float* h1in = (float*)carve((size_t)N1C * HC * 4);
  float* acc1 = (float*)carve((size_t)N1C * HC * 4);
  float* hc1  = (float*)carve((size_t)N1C * HC * 4);
  float* cB0 = (float*)carve((size_t)HC * HC * 4);
  float* sB0 = (float*)carve((size_t)HC * HC * 4);
  float* cB1 = (float*)carve((size_t)HC * HC * 4);
  float* sB1 = (float*)carve((size_t)HC * HC * 4);
  float* d0 = (float*)carve((size_t)(E0C + N0C) * 4);
  float* d1 = (float*)carve((size_t)(E1C + N1C) * 4);
  // dynamic edge-chunk so sA/cA/t always fit in ws
  size_t used = (size_t)(p - (char*)d_ws);
  size_t avail = ws_size > used ? ws_size - used : (size_t)0;
  long long capll = (long long)(avail / (3 * HC * 4 + 32));
  int cap = capll > (E0C + N0C) ? (E0C + N0C) : (int)capll;
  cap &= ~3;
  if (cap < 4) cap = 4;  // last resort; ws assumed sane
  float* sAb = (float*)carve((size_t)cap * HC * 4);
  float* cAb = (float*)carve((size_t)cap * HC * 4);
  float* tb  = (float*)carve((size_t)cap * HC * 4);

  hipMemsetAsync(acc0, 0, (size_t)N0C * HC * 4, stream);
  hipMemsetAsync(acc1, 0, (size_t)N1C * HC * 4, stream);
  hipMemsetAsync(pb, 0, (size_t)N0C * HC * 4, stream);

  k_encoder<<<(N0C * HC) / 256, 256, 0, stream>>>(x, l0w, l0b, h0);
  k_chanprep<<<(HC * HC) / 256, 256, 0, stream>>>(c0w0, cB0, sB0);
  const int E0T = E0C + N0C;
  for (int base = 0; base < E0T; base += cap) {
    int len = (E0T - base) < cap ? (E0T - base) : cap;
    k_edgeprep<<<len, 64, 0, stream>>>(ei, E0C, base, pos, h0, c0w0, c0b0, c0w2, c0b2,
                                       sAb, cAb, tb, d0);
    k_conv<<<1024, 256, 0, stream>>>(ei, E0C, base, len, sAb, cAb, tb, d0,
                                     cB0, sB0, c0w1, c0b1, acc0);
  }
  k_postsin<<<(N0C * HC) / 256, 256, 0, stream>>>(acc0, c0bias, hc0, N0C * HC);
  k_poolmax<<<(E0T * HC) / 256, 256, 0, stream>>>(ei, hc0, pb);
  k_gather<<<(N1C * HC) / 256, 256, 0, stream>>>(pb, keep, h1in);

  k_chanprep<<<(HC * HC) / 256, 256, 0, stream>>>(c1w0, cB1, sB1);
  const int E1T = E1C + N1C;
  for (int base = 0; base < E1T; base += cap) {
    int len = (E1T - base) < cap ? (E1T - base) : cap;
    k_edgeprep<<<len, 64, 0, stream>>>(pei, E1C, base, ppos, h1in, c1w0, c1b0, c1w2, c1b2,
                                       sAb, cAb, tb, d1);
    k_conv<<<1024, 256, 0, stream>>>(pei, E1C, base, len, sAb, cAb, tb, d1,
                                     cB1, sB1, c1w1, c1b1, acc1);
  }
  k_postsin<<<(N1C * HC) / 256, 256, 0, stream>>>(acc1, c1bias, hc1, N1C * HC);
  k_final<<<(N1C * LATC) / 256, 256, 0, stream>>>(hc1, l1w, l1b, outp);
}